// Round 1
// baseline (3299.269 us; speedup 1.0000x reference)
//
#include <hip/hip_runtime.h>
#include <hip/hip_bf16.h>

#define Bn   32
#define Sn   2048
#define Dn   768
#define QDn  256
#define OUTn 1024

// ---------------------------------------------------------------------------
// Kernel A: Q = data @ W1^T + b1 ; K = data @ W2^T + b2
// grid (8 n-tiles, 1024 m-tiles), 256 threads, 64x64x32 tiles.
// LDS tiles stored [k][m] (pad 68 keeps rows 16B-aligned, banks <=2-way)
// so compute reads are float4 (ds_read_b128).
// ---------------------------------------------------------------------------
__global__ __launch_bounds__(256) void proj_kernel(
    const float* __restrict__ data,
    const float* __restrict__ W1, const float* __restrict__ b1,
    const float* __restrict__ W2, const float* __restrict__ b2,
    float* __restrict__ Qb, float* __restrict__ Kb)
{
    __shared__ float As[32][68];
    __shared__ float Bs[32][68];
    const int tid = threadIdx.x;
    const int tx = tid & 15, ty = tid >> 4;
    const int m0 = blockIdx.y << 6;
    const int n0 = blockIdx.x << 6;            // 0..511 over [Q|K]
    const bool isQ = (n0 < QDn);               // uniform per block
    const float* W    = isQ ? W1 : W2;
    const float* bias = isQ ? b1 : b2;
    float* outb = isQ ? Qb : Kb;
    const int nw0 = isQ ? n0 : (n0 - QDn);

    float acc[4][4] = {};

    for (int kt = 0; kt < Dn; kt += 32) {
        #pragma unroll
        for (int g = 0; g < 2; ++g) {
            const int l   = tid + (g << 8);
            const int row = l >> 3;
            const int k4  = (l & 7) << 2;
            const float4 va = *(const float4*)(data + (size_t)(m0 + row) * Dn + kt + k4);
            As[k4+0][row] = va.x; As[k4+1][row] = va.y;
            As[k4+2][row] = va.z; As[k4+3][row] = va.w;
            const float4 vb = *(const float4*)(W + (size_t)(nw0 + row) * Dn + kt + k4);
            Bs[k4+0][row] = vb.x; Bs[k4+1][row] = vb.y;
            Bs[k4+2][row] = vb.z; Bs[k4+3][row] = vb.w;
        }
        __syncthreads();
        #pragma unroll
        for (int k = 0; k < 32; ++k) {
            const float4 a = *(const float4*)&As[k][ty << 2];
            const float4 b = *(const float4*)&Bs[k][tx << 2];
            const float av[4] = {a.x, a.y, a.z, a.w};
            const float bv[4] = {b.x, b.y, b.z, b.w};
            #pragma unroll
            for (int i = 0; i < 4; ++i)
                #pragma unroll
                for (int j = 0; j < 4; ++j)
                    acc[i][j] += av[i] * bv[j];
        }
        __syncthreads();
    }

    #pragma unroll
    for (int i = 0; i < 4; ++i) {
        const int m = m0 + (ty << 2) + i;
        const int n = nw0 + (tx << 2);
        float4 o;
        o.x = acc[i][0] + bias[n + 0];
        o.y = acc[i][1] + bias[n + 1];
        o.z = acc[i][2] + bias[n + 2];
        o.w = acc[i][3] + bias[n + 3];
        *(float4*)(outb + (size_t)m * QDn + n) = o;
    }
}

// ---------------------------------------------------------------------------
// Kernel B: flash attention + per-block column max.
// grid (32 i-tiles, 32 batches), 256 threads (tx 0..15, ty 0..15).
// Per block: rows i0..i0+63. Loop j-tiles of 64:
//   scores S = Ki . Qj^T / 16 (k-chunked GEMM, 4x4 per thread)
//   online softmax per row (16-lane shuffle reductions; row group = same ty)
//   P -> LDS, PV accumulate x_acc[4 rows][16 cols] (col q = g*64 + tx*4 + v)
// Epilogue: x /= l, column max over the 64 rows, write partial max.
// LDS ~50.3 KB -> 2-3 blocks/CU.
// ---------------------------------------------------------------------------
__global__ __launch_bounds__(256, 2) void attn_kernel(
    const float* __restrict__ Qb, const float* __restrict__ Kb,
    float* __restrict__ pmax)
{
    __shared__ float Kic[32][68];
    __shared__ float Qjc[32][68];
    __shared__ float Pl[64][68];
    __shared__ float Kv[16][260];

    const int tid = threadIdx.x;
    const int tx = tid & 15, ty = tid >> 4;
    const int b  = blockIdx.y;
    const int i0 = blockIdx.x << 6;

    float x_acc[4][16];
    float m_i[4], l_i[4];
    #pragma unroll
    for (int r = 0; r < 4; ++r) {
        m_i[r] = -INFINITY; l_i[r] = 0.f;
        #pragma unroll
        for (int c = 0; c < 16; ++c) x_acc[r][c] = 0.f;
    }

    const size_t base = (size_t)b * Sn * QDn;

    for (int jt = 0; jt < Sn; jt += 64) {
        float Sc[4][4] = {};
        // ---- scores: Ki (64xk) . Qj (64xk)^T, k-chunks of 32 ----
        for (int kc = 0; kc < QDn; kc += 32) {
            #pragma unroll
            for (int g = 0; g < 2; ++g) {
                const int l   = tid + (g << 8);
                const int row = l >> 3;
                const int k4  = (l & 7) << 2;
                const float4 vk = *(const float4*)(Kb + base + (size_t)(i0 + row) * QDn + kc + k4);
                Kic[k4+0][row] = vk.x; Kic[k4+1][row] = vk.y;
                Kic[k4+2][row] = vk.z; Kic[k4+3][row] = vk.w;
                const float4 vq = *(const float4*)(Qb + base + (size_t)(jt + row) * QDn + kc + k4);
                Qjc[k4+0][row] = vq.x; Qjc[k4+1][row] = vq.y;
                Qjc[k4+2][row] = vq.z; Qjc[k4+3][row] = vq.w;
            }
            __syncthreads();
            #pragma unroll
            for (int k = 0; k < 32; ++k) {
                const float4 a = *(const float4*)&Kic[k][ty << 2];
                const float4 q = *(const float4*)&Qjc[k][tx << 2];
                const float av[4] = {a.x, a.y, a.z, a.w};
                const float qv[4] = {q.x, q.y, q.z, q.w};
                #pragma unroll
                for (int r = 0; r < 4; ++r)
                    #pragma unroll
                    for (int c = 0; c < 4; ++c)
                        Sc[r][c] += av[r] * qv[c];
            }
            __syncthreads();
        }
        // ---- online softmax (rows r live on the 16 lanes sharing ty) ----
        #pragma unroll
        for (int r = 0; r < 4; ++r) {
            #pragma unroll
            for (int c = 0; c < 4; ++c) Sc[r][c] *= 0.0625f;   // 1/sqrt(256)
            float mx = fmaxf(fmaxf(Sc[r][0], Sc[r][1]), fmaxf(Sc[r][2], Sc[r][3]));
            #pragma unroll
            for (int off = 1; off < 16; off <<= 1) mx = fmaxf(mx, __shfl_xor(mx, off, 64));
            const float mnew = fmaxf(m_i[r], mx);
            const float al   = __expf(m_i[r] - mnew);          // exp(-inf)=0 on first tile
            float rs = 0.f;
            #pragma unroll
            for (int c = 0; c < 4; ++c) {
                const float p = __expf(Sc[r][c] - mnew);
                Sc[r][c] = p; rs += p;
            }
            #pragma unroll
            for (int off = 1; off < 16; off <<= 1) rs += __shfl_xor(rs, off, 64);
            l_i[r] = l_i[r] * al + rs;
            m_i[r] = mnew;
            #pragma unroll
            for (int c = 0; c < 16; ++c) x_acc[r][c] *= al;
        }
        #pragma unroll
        for (int r = 0; r < 4; ++r)
            *(float4*)&Pl[(ty << 2) + r][tx << 2] =
                make_float4(Sc[r][0], Sc[r][1], Sc[r][2], Sc[r][3]);
        __syncthreads();
        // ---- PV: x += P(64x64) . K(64x256), value rows chunked by 16 ----
        for (int jc = 0; jc < 4; ++jc) {
            #pragma unroll
            for (int u = 0; u < 4; ++u) {
                const int g   = tid + (u << 8);
                const int row = g >> 6;
                const int c4  = (g & 63) << 2;
                *(float4*)&Kv[row][c4] =
                    *(const float4*)(Kb + base + (size_t)(jt + (jc << 4) + row) * QDn + c4);
            }
            __syncthreads();
            #pragma unroll
            for (int j = 0; j < 16; ++j) {
                float p[4];
                #pragma unroll
                for (int r = 0; r < 4; ++r) p[r] = Pl[(ty << 2) + r][(jc << 4) + j];
                #pragma unroll
                for (int g2 = 0; g2 < 4; ++g2) {
                    const float4 kv = *(const float4*)&Kv[j][(g2 << 6) + (tx << 2)];
                    const float kvv[4] = {kv.x, kv.y, kv.z, kv.w};
                    #pragma unroll
                    for (int r = 0; r < 4; ++r)
                        #pragma unroll
                        for (int v = 0; v < 4; ++v)
                            x_acc[r][(g2 << 2) + v] += p[r] * kvv[v];
                }
            }
            __syncthreads();
        }
    }

    // ---- epilogue: normalize, column-max over the block's 64 rows ----
    float inv_l[4];
    #pragma unroll
    for (int r = 0; r < 4; ++r) inv_l[r] = 1.0f / l_i[r];
    float* colred = &Kic[0][0];   // alias: 16x256 fits in Kic+Qjc region
    #pragma unroll
    for (int g2 = 0; g2 < 4; ++g2) {
        float tmp[4];
        #pragma unroll
        for (int v = 0; v < 4; ++v) {
            float t = x_acc[0][(g2 << 2) + v] * inv_l[0];
            t = fmaxf(t, x_acc[1][(g2 << 2) + v] * inv_l[1]);
            t = fmaxf(t, x_acc[2][(g2 << 2) + v] * inv_l[2]);
            t = fmaxf(t, x_acc[3][(g2 << 2) + v] * inv_l[3]);
            tmp[v] = t;
        }
        *(float4*)&colred[ty * 256 + (g2 << 6) + (tx << 2)] =
            make_float4(tmp[0], tmp[1], tmp[2], tmp[3]);
    }
    __syncthreads();
    {
        const int q = tid;           // 256 threads <-> 256 feature cols
        float pm = colred[q];
        #pragma unroll
        for (int t = 1; t < 16; ++t) pm = fmaxf(pm, colred[t * 256 + q]);
        pmax[(((size_t)b << 5) + blockIdx.x) * QDn + q] = pm;
    }
}

// ---------------------------------------------------------------------------
// Kernel C: reduce 32 partial maxes per batch, out = relu(xmax @ W3^T + b3)
// grid (32 batches), 256 threads; each thread does 4 outputs (256-dots).
// ---------------------------------------------------------------------------
__global__ __launch_bounds__(256) void head_kernel(
    const float* __restrict__ pmax,
    const float* __restrict__ W3, const float* __restrict__ b3,
    float* __restrict__ out)
{
    __shared__ float xs[QDn];
    const int b = blockIdx.x, tid = threadIdx.x;
    float m = pmax[((size_t)b << 5) * QDn + tid];
    #pragma unroll
    for (int t = 1; t < 32; ++t)
        m = fmaxf(m, pmax[(((size_t)b << 5) + t) * QDn + tid]);
    xs[tid] = m;
    __syncthreads();
    #pragma unroll
    for (int u = 0; u < 4; ++u) {
        const int o = (u << 8) + tid;
        const float4* w = (const float4*)(W3 + (size_t)o * QDn);
        float s = 0.f;
        #pragma unroll 8
        for (int q4 = 0; q4 < QDn / 4; ++q4) {
            const float4 wv = w[q4];
            const float4 xv = *(const float4*)&xs[q4 << 2];
            s += wv.x * xv.x + wv.y * xv.y + wv.z * xv.z + wv.w * xv.w;
        }
        out[(size_t)b * OUTn + o] = fmaxf(s + b3[o], 0.f);
    }
}

// ---------------------------------------------------------------------------
extern "C" void kernel_launch(void* const* d_in, const int* in_sizes, int n_in,
                              void* d_out, int out_size, void* d_ws, size_t ws_size,
                              hipStream_t stream) {
    const float* data = (const float*)d_in[0];
    // d_in[1] = seq_len: unused by the reference computation
    const float* W1 = (const float*)d_in[2];
    const float* b1 = (const float*)d_in[3];
    const float* W2 = (const float*)d_in[4];
    const float* b2 = (const float*)d_in[5];
    const float* W3 = (const float*)d_in[6];
    const float* b3 = (const float*)d_in[7];
    float* out = (float*)d_out;

    // ws layout: Q [B*S*QD] | K [B*S*QD] | pmax [B*32*QD]  (~129 MB)
    float* Qb   = (float*)d_ws;
    float* Kb   = Qb + (size_t)Bn * Sn * QDn;
    float* pmax = Kb + (size_t)Bn * Sn * QDn;

    dim3 gA(8, 1024);
    proj_kernel<<<gA, 256, 0, stream>>>(data, W1, b1, W2, b2, Qb, Kb);
    dim3 gB(Sn / 64, Bn);
    attn_kernel<<<gB, 256, 0, stream>>>(Qb, Kb, pmax);
    head_kernel<<<Bn, 256, 0, stream>>>(pmax, W3, b3, out);
}

// Round 2
// 1449.448 us; speedup vs baseline: 2.2762x; 2.2762x over previous
//
#include <hip/hip_runtime.h>
#include <hip/hip_bf16.h>

#define Bn   32
#define Sn   2048
#define Dn   768
#define QDn  256
#define OUTn 1024

typedef __attribute__((ext_vector_type(8))) short          bf16x8;
typedef __attribute__((ext_vector_type(4))) float          f32x4;
typedef __attribute__((ext_vector_type(8))) unsigned short u16x8;

typedef unsigned short ushort_t;

__device__ __forceinline__ unsigned short f2bf(float f) {
    unsigned int u = __float_as_uint(f);
    u = (u + 0x7FFFu + ((u >> 16) & 1u)) >> 16;   // RNE
    return (unsigned short)u;
}
__device__ __forceinline__ float bf2f(unsigned short h) {
    return __uint_as_float(((unsigned int)h) << 16);
}
// convert 8 fp32 -> bf16 hi + bf16 lo (split)
__device__ __forceinline__ void cvt8(const float4 a, const float4 b, u16x8& h, u16x8& l) {
    float f[8] = {a.x,a.y,a.z,a.w,b.x,b.y,b.z,b.w};
    #pragma unroll
    for (int i = 0; i < 8; ++i) {
        unsigned short hh = f2bf(f[i]);
        h[i] = hh;
        l[i] = f2bf(f[i] - bf2f(hh));
    }
}
#define MFMA16(a,b,c) __builtin_amdgcn_mfma_f32_16x16x32_bf16((a),(b),(c),0,0,0)

// ---------------------------------------------------------------------------
// proj: [Q|K] = data @ W^T + b, split-bf16 MFMA (hh+hl+lh terms).
// grid (2 halves, 512 m-tiles), 256 thr = 4 waves. Block tile 128m x 256n.
// Wave w: rows w*32..w*32+31 (2 msub), all 256 n (16 nsub) -> 32 f32x4 accs.
// Outputs: half0 -> Qh/Ql row-major [65536][256]; half1 -> KTh/KTl [b][q][s].
// ---------------------------------------------------------------------------
__global__ __launch_bounds__(256, 2) void proj_kernel(
    const float* __restrict__ data,
    const float* __restrict__ W1, const float* __restrict__ b1,
    const float* __restrict__ W2, const float* __restrict__ b2,
    ushort_t* __restrict__ Qh, ushort_t* __restrict__ Ql,
    ushort_t* __restrict__ KTh, ushort_t* __restrict__ KTl)
{
    __shared__ __align__(16) char smem[61440];
    ushort_t* DH = (ushort_t*)smem;              // data hi [128][40]
    ushort_t* DL = (ushort_t*)(smem + 10240);    // data lo
    ushort_t* WH = (ushort_t*)(smem + 20480);    // W hi [256][40]
    ushort_t* WL = (ushort_t*)(smem + 40960);    // W lo
    ushort_t* EP = (ushort_t*)smem;              // epilogue overlay

    const int tid  = threadIdx.x;
    const int w    = tid >> 6;
    const int quad = (tid >> 4) & 3;
    const int n15  = tid & 15;
    const int mtile = blockIdx.y;
    const int half  = blockIdx.x;
    const bool isQ  = (half == 0);
    const float* Wp = isQ ? W1 : W2;
    const float* bp = isQ ? b1 : b2;

    f32x4 acc[2][16];
    #pragma unroll
    for (int i = 0; i < 2; ++i)
        #pragma unroll
        for (int j = 0; j < 16; ++j) acc[i][j] = (f32x4)0.f;

    const size_t drow = (size_t)mtile * 128;

    for (int kt = 0; kt < 24; ++kt) {
        const int kc = kt * 32;
        // ---- stage data chunk [128 m][32 k] -> hi/lo, pitch 40 ----
        {
            const int m  = tid >> 1;
            const int k0 = (tid & 1) << 4;
            const float* src = data + (drow + m) * 768 + kc + k0;
            const float4 v0 = *(const float4*)(src);
            const float4 v1 = *(const float4*)(src + 4);
            const float4 v2 = *(const float4*)(src + 8);
            const float4 v3 = *(const float4*)(src + 12);
            u16x8 h0, l0, h1, l1;
            cvt8(v0, v1, h0, l0);
            cvt8(v2, v3, h1, l1);
            *(u16x8*)&DH[m*40 + k0]     = h0;
            *(u16x8*)&DH[m*40 + k0 + 8] = h1;
            *(u16x8*)&DL[m*40 + k0]     = l0;
            *(u16x8*)&DL[m*40 + k0 + 8] = l1;
        }
        // ---- stage W chunk [256 n][32 k] -> hi/lo, pitch 40 ----
        #pragma unroll
        for (int u = 0; u < 4; ++u) {
            const int nrow = (tid >> 2) + u * 64;
            const int ko   = (tid & 3) << 3;
            const float* src = Wp + (size_t)nrow * 768 + kc + ko;
            const float4 v0 = *(const float4*)(src);
            const float4 v1 = *(const float4*)(src + 4);
            u16x8 h, l;
            cvt8(v0, v1, h, l);
            *(u16x8*)&WH[nrow*40 + ko] = h;
            *(u16x8*)&WL[nrow*40 + ko] = l;
        }
        __syncthreads();
        // ---- MFMA: D[m][n] += data[m][k] * W[n][k] ----
        bf16x8 ah[2], al[2];
        #pragma unroll
        for (int ms = 0; ms < 2; ++ms) {
            const int ao = (w*32 + ms*16 + n15)*40 + quad*8;
            ah[ms] = *(bf16x8*)&DH[ao];
            al[ms] = *(bf16x8*)&DL[ao];
        }
        #pragma unroll
        for (int ns = 0; ns < 16; ++ns) {
            const int bo = (ns*16 + n15)*40 + quad*8;
            const bf16x8 bh = *(bf16x8*)&WH[bo];
            const bf16x8 bl = *(bf16x8*)&WL[bo];
            #pragma unroll
            for (int ms = 0; ms < 2; ++ms) {
                acc[ms][ns] = MFMA16(ah[ms], bh, acc[ms][ns]);
                acc[ms][ns] = MFMA16(ah[ms], bl, acc[ms][ns]);
                acc[ms][ns] = MFMA16(al[ms], bh, acc[ms][ns]);
            }
        }
        __syncthreads();
    }

    // bias per nsub (col n = ns*16 + n15)
    float bv[16];
    #pragma unroll
    for (int ns = 0; ns < 16; ++ns) bv[ns] = bp[ns*16 + n15];

    if (isQ) {
        // write Q row-major via LDS roundtrip, rounds = (row-half, precision)
        #pragma unroll
        for (int hf = 0; hf < 2; ++hf) {
            #pragma unroll
            for (int pr = 0; pr < 2; ++pr) {
                __syncthreads();
                if ((w >> 1) == hf) {
                    #pragma unroll
                    for (int ms = 0; ms < 2; ++ms)
                        #pragma unroll
                        for (int ns = 0; ns < 16; ++ns)
                            #pragma unroll
                            for (int r = 0; r < 4; ++r) {
                                const int rl = (w & 1)*32 + ms*16 + quad*4 + r;
                                const float v = acc[ms][ns][r] + bv[ns];
                                const unsigned short hh = f2bf(v);
                                const unsigned short val = pr ? f2bf(v - bf2f(hh)) : hh;
                                EP[rl*264 + ns*16 + n15] = val;
                            }
                }
                __syncthreads();
                ushort_t* dst = pr ? Ql : Qh;
                const int row = tid >> 2;
                #pragma unroll
                for (int u = 0; u < 8; ++u) {
                    const int co = (tid & 3)*8 + u*32;
                    *(u16x8*)(dst + (drow + hf*64 + row)*256 + co) =
                        *(u16x8*)&EP[row*264 + co];
                }
            }
        }
    } else {
        // write K transposed: KT[b][q][s], rounds = (q-half, precision)
        const int bidx = mtile >> 4;
        const int s0   = (mtile & 15) * 128;
        #pragma unroll
        for (int qh = 0; qh < 2; ++qh) {
            #pragma unroll
            for (int pr = 0; pr < 2; ++pr) {
                __syncthreads();
                #pragma unroll
                for (int ms = 0; ms < 2; ++ms)
                    #pragma unroll
                    for (int ns8 = 0; ns8 < 8; ++ns8) {
                        const int ns = qh*8 + ns8;
                        #pragma unroll
                        for (int r = 0; r < 4; ++r) {
                            const int rowm = w*32 + ms*16 + quad*4 + r;
                            const int qloc = ns8*16 + n15;
                            const float v = acc[ms][ns][r] + bv[ns];
                            const unsigned short hh = f2bf(v);
                            const unsigned short val = pr ? f2bf(v - bf2f(hh)) : hh;
                            EP[qloc*136 + rowm] = val;
                        }
                    }
                __syncthreads();
                ushort_t* dst = pr ? KTl : KTh;
                const int q = tid >> 1;
                #pragma unroll
                for (int u = 0; u < 8; ++u) {
                    const int mo = (tid & 1)*8 + u*16;
                    *(u16x8*)(dst + ((size_t)(bidx*256 + qh*128 + q))*2048 + s0 + mo) =
                        *(u16x8*)&EP[q*136 + mo];
                }
            }
        }
    }
}

// ---------------------------------------------------------------------------
// attn: flash attention, split-bf16 MFMA, S^T formulation.
// grid (32 i-tiles, 32 b), 256 thr = 4 waves; wave w owns i-cols w*16..+15.
// Scores: D[j][i] = sum_q Q[j][q]*K[i][q]; A=Q (LDS chunks), B=K_i (regs).
// PV: D[q][i] = sum_j KT[q][j]*P[i][j]; A=KT (LDS chunks), B=P (LDS, [i][j]).
// Per-lane scalar online-softmax state (m,l) for i = i0 + w*16 + (lane&15).
// ---------------------------------------------------------------------------
__global__ __launch_bounds__(256, 2) void attn_kernel(
    const ushort_t* __restrict__ Qh, const ushort_t* __restrict__ Ql,
    const ushort_t* __restrict__ KTh, const ushort_t* __restrict__ KTl,
    float* __restrict__ pmax)
{
    __shared__ __align__(16) char smem[55296];
    ushort_t* SB_h = (ushort_t*)smem;              // staging: Q chunk [64][136] or KT chunk [128][72]
    ushort_t* SB_l = (ushort_t*)(smem + 18432);
    ushort_t* PB_h = (ushort_t*)(smem + 36864);    // P [64 i][72 j]
    ushort_t* PB_l = (ushort_t*)(smem + 46080);
    float*    REDf = (float*)smem;                 // epilogue overlay [4][256]

    const int tid  = threadIdx.x;
    const int w    = tid >> 6;
    const int quad = (tid >> 4) & 3;
    const int n15  = tid & 15;
    const int b    = blockIdx.y;
    const int i0   = blockIdx.x << 6;
    const int iw   = i0 + w*16 + n15;              // this lane's i (B-frag col)

    const ushort_t* QhB  = Qh  + (size_t)b * Sn * QDn;
    const ushort_t* QlB  = Ql  + (size_t)b * Sn * QDn;
    const ushort_t* KThB = KTh + (size_t)b * QDn * Sn;
    const ushort_t* KTlB = KTl + (size_t)b * QDn * Sn;

    // ---- persistent B-frags: K_i rows, 8 k-steps, hi+lo (loaded from KT) ----
    bf16x8 kfh[8], kfl[8];
    #pragma unroll
    for (int ks = 0; ks < 8; ++ks) {
        #pragma unroll
        for (int e = 0; e < 8; ++e) {
            const size_t g = (size_t)(ks*32 + quad*8 + e) * Sn + iw;
            kfh[ks][e] = (short)KThB[g];
            kfl[ks][e] = (short)KTlB[g];
        }
    }

    f32x4 xq[16];
    #pragma unroll
    for (int i = 0; i < 16; ++i) xq[i] = (f32x4)0.f;
    float m_i = -INFINITY, l_i = 0.f;

    for (int jt = 0; jt < Sn; jt += 64) {
        f32x4 sc[4];
        #pragma unroll
        for (int i = 0; i < 4; ++i) sc[i] = (f32x4)0.f;

        // ---- scores: 2 k-chunks of 128 ----
        #pragma unroll
        for (int kc2 = 0; kc2 < 2; ++kc2) {
            const int kc = kc2 * 128;
            #pragma unroll
            for (int u = 0; u < 4; ++u) {
                const int j  = (tid >> 4) + u*16;
                const int ko = (tid & 15) << 3;
                const size_t g = (size_t)(jt + j) * QDn + kc + ko;
                *(u16x8*)&SB_h[j*136 + ko] = *(const u16x8*)(QhB + g);
                *(u16x8*)&SB_l[j*136 + ko] = *(const u16x8*)(QlB + g);
            }
            __syncthreads();
            #pragma unroll
            for (int ks2 = 0; ks2 < 4; ++ks2) {
                const int gks = kc2*4 + ks2;
                #pragma unroll
                for (int js = 0; js < 4; ++js) {
                    const int ao = (js*16 + n15)*136 + ks2*32 + quad*8;
                    const bf16x8 ah = *(bf16x8*)&SB_h[ao];
                    const bf16x8 al = *(bf16x8*)&SB_l[ao];
                    sc[js] = MFMA16(ah, kfh[gks], sc[js]);
                    sc[js] = MFMA16(ah, kfl[gks], sc[js]);
                    sc[js] = MFMA16(al, kfh[gks], sc[js]);
                }
            }
            __syncthreads();
        }

        // ---- online softmax (per-lane scalar state; rows of S^T = j) ----
        float s[16];
        float mx = -INFINITY;
        #pragma unroll
        for (int js = 0; js < 4; ++js)
            #pragma unroll
            for (int r = 0; r < 4; ++r) {
                const float v = sc[js][r] * 0.0625f;
                s[js*4 + r] = v;
                mx = fmaxf(mx, v);
            }
        mx = fmaxf(mx, __shfl_xor(mx, 16, 64));
        mx = fmaxf(mx, __shfl_xor(mx, 32, 64));
        const float mnew = fmaxf(m_i, mx);
        const float al_  = __expf(m_i - mnew);
        float rs = 0.f;
        #pragma unroll
        for (int k = 0; k < 16; ++k) {
            const float p = __expf(s[k] - mnew);
            s[k] = p;
            rs += p;
        }
        rs += __shfl_xor(rs, 16, 64);
        rs += __shfl_xor(rs, 32, 64);
        l_i = l_i * al_ + rs;
        m_i = mnew;
        #pragma unroll
        for (int i = 0; i < 16; ++i) xq[i] *= al_;
        // write P (split) to LDS [i][j]
        #pragma unroll
        for (int js = 0; js < 4; ++js)
            #pragma unroll
            for (int r = 0; r < 4; ++r) {
                const float p = s[js*4 + r];
                const unsigned short hh = f2bf(p);
                const int ad = (w*16 + n15)*72 + js*16 + quad*4 + r;
                PB_h[ad] = hh;
                PB_l[ad] = f2bf(p - bf2f(hh));
            }

        // ---- PV: 2 q-chunks of 128 ----
        #pragma unroll
        for (int qc2 = 0; qc2 < 2; ++qc2) {
            #pragma unroll
            for (int u = 0; u < 4; ++u) {
                const int q  = (tid >> 3) + u*32;
                const int jo = (tid & 7) << 3;
                const size_t g = (size_t)(qc2*128 + q) * Sn + jt + jo;
                *(u16x8*)&SB_h[q*72 + jo] = *(const u16x8*)(KThB + g);
                *(u16x8*)&SB_l[q*72 + jo] = *(const u16x8*)(KTlB + g);
            }
            __syncthreads();
            bf16x8 pbh[2], pbl[2];
            #pragma unroll
            for (int js2 = 0; js2 < 2; ++js2) {
                const int po = (w*16 + n15)*72 + js2*32 + quad*8;
                pbh[js2] = *(bf16x8*)&PB_h[po];
                pbl[js2] = *(bf16x8*)&PB_l[po];
            }
            #pragma unroll
            for (int qs = 0; qs < 8; ++qs) {
                #pragma unroll
                for (int js2 = 0; js2 < 2; ++js2) {
                    const int ao = (qs*16 + n15)*72 + js2*32 + quad*8;
                    const bf16x8 ah = *(bf16x8*)&SB_h[ao];
                    const bf16x8 al2 = *(bf16x8*)&SB_l[ao];
                    f32x4 x = xq[qc2*8 + qs];
                    x = MFMA16(ah, pbh[js2], x);
                    x = MFMA16(ah, pbl[js2], x);
                    x = MFMA16(al2, pbh[js2], x);
                    xq[qc2*8 + qs] = x;
                }
            }
            __syncthreads();
        }
    }

    // ---- epilogue: normalize, max over this block's 64 i, write partial ----
    const float invl = 1.0f / l_i;
    #pragma unroll
    for (int qs = 0; qs < 16; ++qs)
        #pragma unroll
        for (int r = 0; r < 4; ++r) {
            float v = xq[qs][r] * invl;
            v = fmaxf(v, __shfl_xor(v, 1, 64));
            v = fmaxf(v, __shfl_xor(v, 2, 64));
            v = fmaxf(v, __shfl_xor(v, 4, 64));
            v = fmaxf(v, __shfl_xor(v, 8, 64));
            if (n15 == 0) REDf[w*256 + qs*16 + quad*4 + r] = v;
        }
    __syncthreads();
    {
        float pm = REDf[tid];
        #pragma unroll
        for (int ww = 1; ww < 4; ++ww) pm = fmaxf(pm, REDf[ww*256 + tid]);
        pmax[((size_t)b * 32 + blockIdx.x) * QDn + tid] = pm;
    }
}

// ---------------------------------------------------------------------------
// head: reduce partial maxes, out = relu(xmax @ W3^T + b3). fp32.
// ---------------------------------------------------------------------------
__global__ __launch_bounds__(256) void head_kernel(
    const float* __restrict__ pmax,
    const float* __restrict__ W3, const float* __restrict__ b3,
    float* __restrict__ out)
{
    __shared__ float xs[QDn];
    const int b = blockIdx.x, tid = threadIdx.x;
    float m = pmax[((size_t)b << 5) * QDn + tid];
    #pragma unroll
    for (int t = 1; t < 32; ++t)
        m = fmaxf(m, pmax[(((size_t)b << 5) + t) * QDn + tid]);
    xs[tid] = m;
    __syncthreads();
    #pragma unroll
    for (int u = 0; u < 4; ++u) {
        const int o = (u << 8) + tid;
        const float4* wv = (const float4*)(W3 + (size_t)o * QDn);
        float s = 0.f;
        #pragma unroll 8
        for (int q4 = 0; q4 < QDn / 4; ++q4) {
            const float4 w4 = wv[q4];
            const float4 x4 = *(const float4*)&xs[q4 << 2];
            s += w4.x * x4.x + w4.y * x4.y + w4.z * x4.z + w4.w * x4.w;
        }
        out[(size_t)b * OUTn + o] = fmaxf(s + b3[o], 0.f);
    }
}

// ---------------------------------------------------------------------------
extern "C" void kernel_launch(void* const* d_in, const int* in_sizes, int n_in,
                              void* d_out, int out_size, void* d_ws, size_t ws_size,
                              hipStream_t stream) {
    const float* data = (const float*)d_in[0];
    // d_in[1] = seq_len: unused by the reference computation
    const float* W1 = (const float*)d_in[2];
    const float* b1 = (const float*)d_in[3];
    const float* W2 = (const float*)d_in[4];
    const float* b2 = (const float*)d_in[5];
    const float* W3 = (const float*)d_in[6];
    const float* b3 = (const float*)d_in[7];
    float* out = (float*)d_out;

    // ws: Qh | Ql | KTh | KTl (each 16777216 u16 = 32 MB) | pmax (1 MB)
    ushort_t* Qh  = (ushort_t*)d_ws;
    ushort_t* Ql  = Qh  + 16777216;
    ushort_t* KTh = Ql  + 16777216;
    ushort_t* KTl = KTh + 16777216;
    float*    pmax = (float*)((char*)d_ws + 134217728);

    dim3 gP(2, 512);
    proj_kernel<<<gP, 256, 0, stream>>>(data, W1, b1, W2, b2, Qh, Ql, KTh, KTl);
    dim3 gA(Sn / 64, Bn);
    attn_kernel<<<gA, 256, 0, stream>>>(Qh, Ql, KTh, KTl, pmax);
    head_kernel<<<Bn, 256, 0, stream>>>(pmax, W3, b3, out);
}